// Round 2
// baseline (268.173 us; speedup 1.0000x reference)
//
#include <hip/hip_runtime.h>
#include <hip/hip_bf16.h>

#define HSZ 128
#define WSZ 128
#define HWSZ (HSZ*WSZ)      // 16384
#define NB 4

// ws layout (float offsets)
#define OFF_MB 0            // NPIX*4 floats: mask bias per (pixel, p)

typedef unsigned short u16;
typedef __attribute__((ext_vector_type(8))) short bf16x8;
typedef __attribute__((ext_vector_type(4))) float f32x4;

__device__ __forceinline__ float bf2f(u16 u) {
    return __uint_as_float(((unsigned int)u) << 16);
}
// packed fp32x2 -> bf16x2 (v_cvt_pk_bf16_f32 on gfx950), RNE
__device__ __forceinline__ unsigned int cvt_pk_bf16(float lo, float hi) {
    __hip_bfloat162 h = __float22bfloat162_rn(make_float2(lo, hi));
    return *(unsigned int*)&h;
}
// A-frag slot swizzle: bijective on 0..63, spreads 16B slot starts over banks
__device__ __forceinline__ int sswz(int s) { return s ^ (s >> 3); }
// lane's W-fragment: W[drow][k0..k0+7] as bf16 (lane&15 -> row/col, quad -> k-group)
__device__ __forceinline__ bf16x8 load_bfrag(const float* W, int drow, int k0) {
    float4 a = *(const float4*)(W + drow*64 + k0);
    float4 b = *(const float4*)(W + drow*64 + k0 + 4);
    unsigned int u[4];
    u[0] = cvt_pk_bf16(a.x, a.y); u[1] = cvt_pk_bf16(a.z, a.w);
    u[2] = cvt_pk_bf16(b.x, b.y); u[3] = cvt_pk_bf16(b.z, b.w);
    return *(bf16x8*)u;
}

// ---------------- Kernel 1: mask branch -> mb[pix][p] ----------------------
// mb = colmean(pw_w) . gelu(dwconv3x3(mask)+dw_b)   (mean(pw_b) cancels)
__global__ __launch_bounds__(1024) void mask_kernel(const float* __restrict__ mask,
                                                    const float* __restrict__ dww,
                                                    const float* __restrict__ dwb,
                                                    const float* __restrict__ pww,
                                                    float* __restrict__ ws) {
    __shared__ float red[4][256][4];   // 16 KB
    __shared__ float cmS[64];
    int tid = threadIdx.x;
    if (tid < 64) {                    // fold colmean(pw_w) into this kernel
        float s = 0.f;
        for (int co = 0; co < 64; ++co) s += pww[co*64 + tid];
        cmS[tid] = s * (1.0f/64.0f);
    }
    __syncthreads();
    int bid = blockIdx.x;              // 256 blocks: [bp(16)][hgroup(16)]
    int bp = bid >> 4;
    int hg = bid & 15;
    int cq = tid >> 8;                 // channel quarter 0..3
    int t = tid & 255;                 // pixel slot: 8 rows x 32 colgroups
    int h = hg*8 + (t >> 5);
    int w0 = (t & 31) << 2;
    const float* mb_ = mask + (size_t)bp*64*HWSZ;
    int hm = h > 0 ? h-1 : 0;
    int hp = h < 127 ? h+1 : 127;
    float vt = h > 0 ? 1.f : 0.f;
    float vb = h < 127 ? 1.f : 0.f;
    float vl = w0 > 0 ? 1.f : 0.f;
    float vr = w0 < 124 ? 1.f : 0.f;
    int wl = w0 > 0 ? w0-1 : 0;
    int wr = w0 < 124 ? w0+4 : 127;
    float acc0=0.f, acc1=0.f, acc2=0.f, acc3=0.f;
    for (int ci = 0; ci < 16; ++ci) {
        int c = cq*16 + ci;
        const float* rc = mb_ + c*HWSZ;
        const float* r0 = rc + hm*WSZ;
        const float* r1 = rc + h*WSZ;
        const float* r2 = rc + hp*WSZ;
        float4 m0 = *(const float4*)(r0 + w0);
        float4 m1 = *(const float4*)(r1 + w0);
        float4 m2 = *(const float4*)(r2 + w0);
        float L0 = r0[wl]*vl, L1 = r1[wl]*vl, L2 = r2[wl]*vl;
        float R0 = r0[wr]*vr, R1 = r1[wr]*vr, R2 = r2[wr]*vr;
        float w00 = dww[c*9+0]*vt, w01 = dww[c*9+1]*vt, w02 = dww[c*9+2]*vt;
        float w10 = dww[c*9+3],    w11 = dww[c*9+4],    w12 = dww[c*9+5];
        float w20 = dww[c*9+6]*vb, w21 = dww[c*9+7]*vb, w22 = dww[c*9+8]*vb;
        float bb = dwb[c];
        float s0 = bb + w00*L0   + w01*m0.x + w02*m0.y
                      + w10*L1   + w11*m1.x + w12*m1.y
                      + w20*L2   + w21*m2.x + w22*m2.y;
        float s1 = bb + w00*m0.x + w01*m0.y + w02*m0.z
                      + w10*m1.x + w11*m1.y + w12*m1.z
                      + w20*m2.x + w21*m2.y + w22*m2.z;
        float s2 = bb + w00*m0.y + w01*m0.z + w02*m0.w
                      + w10*m1.y + w11*m1.z + w12*m1.w
                      + w20*m2.y + w21*m2.z + w22*m2.w;
        float s3 = bb + w00*m0.z + w01*m0.w + w02*R0
                      + w10*m1.z + w11*m1.w + w12*R1
                      + w20*m2.z + w21*m2.w + w22*R2;
        float cmc = cmS[c];
        acc0 += cmc * (0.5f*s0*(1.f + erff(s0*0.70710678118654752f)));
        acc1 += cmc * (0.5f*s1*(1.f + erff(s1*0.70710678118654752f)));
        acc2 += cmc * (0.5f*s2*(1.f + erff(s2*0.70710678118654752f)));
        acc3 += cmc * (0.5f*s3*(1.f + erff(s3*0.70710678118654752f)));
    }
    red[cq][t][0] = acc0;
    red[cq][t][1] = acc1;
    red[cq][t][2] = acc2;
    red[cq][t][3] = acc3;
    __syncthreads();
    if (tid < 256) {
        int b = bp >> 2, p = bp & 3;
        size_t base = (size_t)b*HWSZ + h*WSZ + w0;
        #pragma unroll
        for (int e = 0; e < 4; ++e) {
            float v = red[0][tid][e] + red[1][tid][e] + red[2][tid][e] + red[3][tid][e];
            ws[OFF_MB + (base+e)*4 + p] = v;
        }
    }
}

// ---------------- Kernel 2: MFMA qkv + attention + MFMA proj ---------------
// 16 px/block, 512 thr, 32 KB LDS -> 4 blocks/CU = 32 waves/CU.
// Transposed MFMA (A=W, B=x): D[d][token]; lane holds 4 consecutive d for one
// token -> b64 QKV stores, direct coalesced global store for proj output.
// Phase 2: p = lane&3 -> quad holds all 4 polarizations; cross-p via DPP shfl.
__global__ __launch_bounds__(512, 8) void attn_kernel(const float* __restrict__ x_in,
                                                      const float* __restrict__ wq,
                                                      const float* __restrict__ wk,
                                                      const float* __restrict__ wv,
                                                      const float* __restrict__ wp,
                                                      const float* __restrict__ bpj,
                                                      const float* __restrict__ rsc,
                                                      const float* __restrict__ ws,
                                                      float* __restrict__ out) {
    __shared__ u16 smem[16384];           // 32 KB
    u16* ldsA = smem;                     // 8 KB: x then y, swizzled A-frag order
    u16* ldsQ = smem + 4096;              // 8 KB each: [token(64)][granule-swz d(64)]
    u16* ldsK = smem + 8192;
    u16* ldsV = smem + 12288;
    unsigned int* ldsA32 = (unsigned int*)ldsA;

    int t = threadIdx.x;
    int lane = t & 63;
    int wid = __builtin_amdgcn_readfirstlane(t >> 6);  // 0..7
    int dq = wid & 3;                     // d-quarter
    int half = wid >> 2;                  // token half (mt 0..1 / 2..3)
    int n15 = lane & 15;
    int quad = lane >> 4;
    int b = blockIdx.x >> 10;             // 4096 blocks = 4 b x 1024
    int hw0 = (blockIdx.x & 1023) << 4;

    // QKV W-fragments (bf16) for this wave's d-quarter (proj frags loaded in ph3)
    bf16x8 fq0 = load_bfrag(wq, dq*16 + n15, quad*8);
    bf16x8 fq1 = load_bfrag(wq, dq*16 + n15, 32 + quad*8);
    bf16x8 fk0 = load_bfrag(wk, dq*16 + n15, quad*8);
    bf16x8 fk1 = load_bfrag(wk, dq*16 + n15, 32 + quad*8);
    bf16x8 fv0 = load_bfrag(wv, dq*16 + n15, quad*8);
    bf16x8 fv1 = load_bfrag(wv, dq*16 + n15, 32 + quad*8);

    // stage x -> ldsA (A-frag layout, 16 KB x-tile: 64 tokens x 64 c)
    {
        int rp = t >> 2, l4 = t & 3;      // rp: [p(4)][cpair(32)], l4: px-quad
        int p = rp >> 5, cp = rp & 31;
        int c0 = cp*2;
        const float* r0 = x_in + (size_t)(b*256 + p*64 + c0)*HWSZ + hw0 + l4*4;
        float4 v0 = *(const float4*)r0;
        float4 v1 = *(const float4*)(r0 + HWSZ);
        int kt = c0 >> 5, qd = (c0 >> 3) & 3, j2 = (c0 & 7) >> 1;
        float a0v[4] = {v0.x, v0.y, v0.z, v0.w};
        float a1v[4] = {v1.x, v1.y, v1.z, v1.w};
        #pragma unroll
        for (int e = 0; e < 4; ++e) {
            int tau = (p << 4) + (l4 << 2) + e;
            int slot = (tau & 15) | (qd << 4);
            ldsA32[((tau >> 4)*2 + kt)*256 + sswz(slot)*4 + j2] = cvt_pk_bf16(a0v[e], a1v[e]);
        }
    }
    __syncthreads();

    // ---- phase 1: Q,K,V GEMMs (transposed: D[d][token]) ----
    int sl8 = sswz(lane)*8;
    for (int m = 0; m < 2; ++m) {
        int mt = half*2 + m;
        bf16x8 a0 = *(const bf16x8*)(ldsA + mt*1024 + sl8);
        bf16x8 a1 = *(const bf16x8*)(ldsA + mt*1024 + 512 + sl8);
        f32x4 aq = {0.f,0.f,0.f,0.f};
        f32x4 ak = {0.f,0.f,0.f,0.f};
        f32x4 av = {0.f,0.f,0.f,0.f};
        aq = __builtin_amdgcn_mfma_f32_16x16x32_bf16(fq0, a0, aq, 0, 0, 0);
        aq = __builtin_amdgcn_mfma_f32_16x16x32_bf16(fq1, a1, aq, 0, 0, 0);
        ak = __builtin_amdgcn_mfma_f32_16x16x32_bf16(fk0, a0, ak, 0, 0, 0);
        ak = __builtin_amdgcn_mfma_f32_16x16x32_bf16(fk1, a1, ak, 0, 0, 0);
        av = __builtin_amdgcn_mfma_f32_16x16x32_bf16(fv0, a0, av, 0, 0, 0);
        av = __builtin_amdgcn_mfma_f32_16x16x32_bf16(fv1, a1, av, 0, 0, 0);
        // lane: token = mt*16+n15, d = dq*16 + quad*4 + r (4 consecutive d)
        // granule swizzle g = (d/4) ^ 2*(token&7): bank-uniform, keeps 16B pairs
        int tg = mt*16 + n15;
        int g = ((dq << 2) + quad) ^ ((n15 & 7) << 1);
        int off = tg*64 + g*4;            // u16 units (g*8 bytes)
        uint2 pq, pk, pv;
        pq.x = cvt_pk_bf16(aq[0], aq[1]); pq.y = cvt_pk_bf16(aq[2], aq[3]);
        pk.x = cvt_pk_bf16(ak[0], ak[1]); pk.y = cvt_pk_bf16(ak[2], ak[3]);
        pv.x = cvt_pk_bf16(av[0], av[1]); pv.y = cvt_pk_bf16(av[2], av[3]);
        *(uint2*)(ldsQ + off) = pq;
        *(uint2*)(ldsK + off) = pk;
        *(uint2*)(ldsV + off) = pv;
    }
    __syncthreads();

    // ---- phase 2: attention core (thread = (pix, head, p); p = lane&3) ----
    {
        int p = t & 3;
        int hd = (t >> 2) & 7;
        int pix = t >> 5;
        int token = (p << 4) + pix;
        int off = token*64 + ((hd ^ (pix & 7)) << 3);   // 16B pair, d=hd*8..+7
        bf16x8 q8 = *(const bf16x8*)(ldsQ + off);
        bf16x8 k8 = *(const bf16x8*)(ldsK + off);
        bf16x8 v8 = *(const bf16x8*)(ldsV + off);
        float qv[8], kv[8];
        float sq = 0.f, sk = 0.f;
        #pragma unroll
        for (int j = 0; j < 8; ++j) {
            qv[j] = bf2f((u16)q8[j]);
            kv[j] = bf2f((u16)k8[j]);
            sq += qv[j]*qv[j];
            sk += kv[j]*kv[j];
        }
        float iq = rsqrtf(fmaxf(sq, 1e-24f));   // == 1/max(||q||,1e-12)
        float ik = rsqrtf(fmaxf(sk, 1e-24f));
        // raw dots vs all 4 key rows (quad_perm shuffles), norms folded into score
        float d0 = 0.f, d1 = 0.f, d2 = 0.f, d3 = 0.f;
        #pragma unroll
        for (int j = 0; j < 8; ++j) {
            float kj = kv[j];
            d0 += qv[j]*kj;
            d1 += qv[j]*__shfl_xor(kj, 1);
            d2 += qv[j]*__shfl_xor(kj, 2);
            d3 += qv[j]*__shfl_xor(kj, 3);
        }
        float mbp = ws[OFF_MB + ((size_t)b*HWSZ + hw0 + pix)*4 + p];
        float iqrs = iq * rsc[hd];
        float s0 = d0*(iqrs*ik)                 + mbp;                  // r = p
        float s1 = d1*(iqrs*__shfl_xor(ik, 1))  + __shfl_xor(mbp, 1);   // r = p^1
        float s2 = d2*(iqrs*__shfl_xor(ik, 2))  + __shfl_xor(mbp, 2);   // r = p^2
        float s3 = d3*(iqrs*__shfl_xor(ik, 3))  + __shfl_xor(mbp, 3);   // r = p^3
        float mx = fmaxf(fmaxf(s0, s1), fmaxf(s2, s3));
        float e0 = __expf(s0-mx), e1 = __expf(s1-mx);
        float e2 = __expf(s2-mx), e3 = __expf(s3-mx);
        float inv = 1.0f / (e0+e1+e2+e3);
        float w0 = e0*inv, w1 = e1*inv, w2 = e2*inv, w3 = e3*inv;
        float y[8];
        #pragma unroll
        for (int j = 0; j < 8; ++j) {
            float vj = bf2f((u16)v8[j]);
            y[j] = w0*vj + w1*__shfl_xor(vj, 1)
                 + w2*__shfl_xor(vj, 2) + w3*__shfl_xor(vj, 3);
        }
        // y -> ldsA A-frag layout (same formula as staging, d = hd*8+j)
        unsigned int pk4[4];
        pk4[0] = cvt_pk_bf16(y[0], y[1]); pk4[1] = cvt_pk_bf16(y[2], y[3]);
        pk4[2] = cvt_pk_bf16(y[4], y[5]); pk4[3] = cvt_pk_bf16(y[6], y[7]);
        int slot = pix | ((hd & 3) << 4);
        *(uint4*)(ldsA32 + (p*2 + (hd >> 2))*256 + sswz(slot)*4) = *(uint4*)pk4;
    }
    __syncthreads();

    // ---- phase 3: proj GEMM + bias, direct store from registers ----
    bf16x8 fp0 = load_bfrag(wp, dq*16 + n15, quad*8);
    bf16x8 fp1 = load_bfrag(wp, dq*16 + n15, 32 + quad*8);
    float4 b4 = *(const float4*)(bpj + dq*16 + quad*4);
    for (int m = 0; m < 2; ++m) {
        int mt = half*2 + m;              // mt == polarization p
        bf16x8 a0 = *(const bf16x8*)(ldsA + mt*1024 + sl8);
        bf16x8 a1 = *(const bf16x8*)(ldsA + mt*1024 + 512 + sl8);
        f32x4 ao = {0.f,0.f,0.f,0.f};
        ao = __builtin_amdgcn_mfma_f32_16x16x32_bf16(fp0, a0, ao, 0, 0, 0);
        ao = __builtin_amdgcn_mfma_f32_16x16x32_bf16(fp1, a1, ao, 0, 0, 0);
        // lane: px = n15, d = dq*16 + quad*4 + r -> 16 lanes x 64B coalesced rows
        size_t obase = ((size_t)((b*4 + mt)*64 + dq*16 + quad*4))*HWSZ + hw0 + n15;
        out[obase]          = ao[0] + b4.x;
        out[obase +   HWSZ] = ao[1] + b4.y;
        out[obase + 2*HWSZ] = ao[2] + b4.z;
        out[obase + 3*HWSZ] = ao[3] + b4.w;
    }
}

extern "C" void kernel_launch(void* const* d_in, const int* in_sizes, int n_in,
                              void* d_out, int out_size, void* d_ws, size_t ws_size,
                              hipStream_t stream) {
    const float* x_in  = (const float*)d_in[0];
    const float* mask  = (const float*)d_in[1];
    const float* wq    = (const float*)d_in[2];
    const float* wk    = (const float*)d_in[3];
    const float* wv    = (const float*)d_in[4];
    const float* wproj = (const float*)d_in[5];
    const float* bproj = (const float*)d_in[6];
    const float* resc  = (const float*)d_in[7];
    const float* dww   = (const float*)d_in[8];
    const float* dwb   = (const float*)d_in[9];
    const float* pww   = (const float*)d_in[10];
    float* ws = (float*)d_ws;
    float* outp = (float*)d_out;

    hipLaunchKernelGGL(mask_kernel, dim3(256), dim3(1024), 0, stream,
                       mask, dww, dwb, pww, ws);
    hipLaunchKernelGGL(attn_kernel, dim3(4096), dim3(512), 0, stream,
                       x_in, wq, wk, wv, wproj, bproj, resc, ws, outp);
}

// Round 3
// 261.154 us; speedup vs baseline: 1.0269x; 1.0269x over previous
//
#include <hip/hip_runtime.h>
#include <hip/hip_bf16.h>

#define HSZ 128
#define WSZ 128
#define HWSZ (HSZ*WSZ)      // 16384
#define NB 4

// ws layout (float offsets)
#define OFF_MB 0            // NPIX*4 floats: mask bias per (pixel, p)

typedef unsigned short u16;
typedef __attribute__((ext_vector_type(8))) short bf16x8;
typedef __attribute__((ext_vector_type(4))) float f32x4;

__device__ __forceinline__ float bf2f(u16 u) {
    return __uint_as_float(((unsigned int)u) << 16);
}
// packed fp32x2 -> bf16x2 (v_cvt_pk_bf16_f32 on gfx950), RNE
__device__ __forceinline__ unsigned int cvt_pk_bf16(float lo, float hi) {
    __hip_bfloat162 h = __float22bfloat162_rn(make_float2(lo, hi));
    return *(unsigned int*)&h;
}
// A-frag slot swizzle: bijective on 0..63, spreads 16B slot starts over banks
__device__ __forceinline__ int sswz(int s) { return s ^ (s >> 3); }
// lane's W-fragment: W[drow][k0..k0+7] as bf16 (lane&15 -> row, quad -> k-group)
__device__ __forceinline__ bf16x8 load_bfrag(const float* W, int drow, int k0) {
    float4 a = *(const float4*)(W + drow*64 + k0);
    float4 b = *(const float4*)(W + drow*64 + k0 + 4);
    unsigned int u[4];
    u[0] = cvt_pk_bf16(a.x, a.y); u[1] = cvt_pk_bf16(a.z, a.w);
    u[2] = cvt_pk_bf16(b.x, b.y); u[3] = cvt_pk_bf16(b.z, b.w);
    return *(bf16x8*)u;
}

// ---------------- Kernel 1: mask branch -> mb[pix][p] ----------------------
// mb = colmean(pw_w) . gelu(dwconv3x3(mask)+dw_b)   (mean(pw_b) cancels)
__global__ __launch_bounds__(1024) void mask_kernel(const float* __restrict__ mask,
                                                    const float* __restrict__ dww,
                                                    const float* __restrict__ dwb,
                                                    const float* __restrict__ pww,
                                                    float* __restrict__ ws) {
    __shared__ float red[4][256][4];   // 16 KB
    __shared__ float cmS[64];
    int tid = threadIdx.x;
    if (tid < 64) {                    // fold colmean(pw_w) into this kernel
        float s = 0.f;
        for (int co = 0; co < 64; ++co) s += pww[co*64 + tid];
        cmS[tid] = s * (1.0f/64.0f);
    }
    __syncthreads();
    int bid = blockIdx.x;              // 256 blocks: [bp(16)][hgroup(16)]
    int bp = bid >> 4;
    int hg = bid & 15;
    int cq = tid >> 8;                 // channel quarter 0..3
    int t = tid & 255;                 // pixel slot: 8 rows x 32 colgroups
    int h = hg*8 + (t >> 5);
    int w0 = (t & 31) << 2;
    const float* mb_ = mask + (size_t)bp*64*HWSZ;
    int hm = h > 0 ? h-1 : 0;
    int hp = h < 127 ? h+1 : 127;
    float vt = h > 0 ? 1.f : 0.f;
    float vb = h < 127 ? 1.f : 0.f;
    float vl = w0 > 0 ? 1.f : 0.f;
    float vr = w0 < 124 ? 1.f : 0.f;
    int wl = w0 > 0 ? w0-1 : 0;
    int wr = w0 < 124 ? w0+4 : 127;
    float acc0=0.f, acc1=0.f, acc2=0.f, acc3=0.f;
    for (int ci = 0; ci < 16; ++ci) {
        int c = cq*16 + ci;
        const float* rc = mb_ + c*HWSZ;
        const float* r0 = rc + hm*WSZ;
        const float* r1 = rc + h*WSZ;
        const float* r2 = rc + hp*WSZ;
        float4 m0 = *(const float4*)(r0 + w0);
        float4 m1 = *(const float4*)(r1 + w0);
        float4 m2 = *(const float4*)(r2 + w0);
        float L0 = r0[wl]*vl, L1 = r1[wl]*vl, L2 = r2[wl]*vl;
        float R0 = r0[wr]*vr, R1 = r1[wr]*vr, R2 = r2[wr]*vr;
        float w00 = dww[c*9+0]*vt, w01 = dww[c*9+1]*vt, w02 = dww[c*9+2]*vt;
        float w10 = dww[c*9+3],    w11 = dww[c*9+4],    w12 = dww[c*9+5];
        float w20 = dww[c*9+6]*vb, w21 = dww[c*9+7]*vb, w22 = dww[c*9+8]*vb;
        float bb = dwb[c];
        float s0 = bb + w00*L0   + w01*m0.x + w02*m0.y
                      + w10*L1   + w11*m1.x + w12*m1.y
                      + w20*L2   + w21*m2.x + w22*m2.y;
        float s1 = bb + w00*m0.x + w01*m0.y + w02*m0.z
                      + w10*m1.x + w11*m1.y + w12*m1.z
                      + w20*m2.x + w21*m2.y + w22*m2.z;
        float s2 = bb + w00*m0.y + w01*m0.z + w02*m0.w
                      + w10*m1.y + w11*m1.z + w12*m1.w
                      + w20*m2.y + w21*m2.z + w22*m2.w;
        float s3 = bb + w00*m0.z + w01*m0.w + w02*R0
                      + w10*m1.z + w11*m1.w + w12*R1
                      + w20*m2.z + w21*m2.w + w22*R2;
        float cmc = cmS[c];
        acc0 += cmc * (0.5f*s0*(1.f + erff(s0*0.70710678118654752f)));
        acc1 += cmc * (0.5f*s1*(1.f + erff(s1*0.70710678118654752f)));
        acc2 += cmc * (0.5f*s2*(1.f + erff(s2*0.70710678118654752f)));
        acc3 += cmc * (0.5f*s3*(1.f + erff(s3*0.70710678118654752f)));
    }
    red[cq][t][0] = acc0;
    red[cq][t][1] = acc1;
    red[cq][t][2] = acc2;
    red[cq][t][3] = acc3;
    __syncthreads();
    if (tid < 256) {
        int b = bp >> 2, p = bp & 3;
        size_t base = (size_t)b*HWSZ + h*WSZ + w0;
        #pragma unroll
        for (int e = 0; e < 4; ++e) {
            float v = red[0][tid][e] + red[1][tid][e] + red[2][tid][e] + red[3][tid][e];
            ws[OFF_MB + (base+e)*4 + p] = v;
        }
    }
}

// ---------------- Kernel 2: MFMA qkv + attention + MFMA proj ---------------
// 32 px/block (128 B rows: full HBM lines), 1024 thr (16 waves), 64 KB LDS
// -> 2 blocks/CU = 32 waves/CU (HW max).
// Transposed MFMA (A=W, B=x): D[d][token]; lane holds 4 consecutive d.
// QKV LDS token' = pix*4 + p (p in LOW bits): phase-2 b128 reads conflict-free
// (R2 had p at token bit 5 -> unfixable 4-way conflict).
__global__ __launch_bounds__(1024, 8) void attn_kernel(const float* __restrict__ x_in,
                                                       const float* __restrict__ wq,
                                                       const float* __restrict__ wk,
                                                       const float* __restrict__ wv,
                                                       const float* __restrict__ wp,
                                                       const float* __restrict__ bpj,
                                                       const float* __restrict__ rsc,
                                                       const float* __restrict__ ws,
                                                       float* __restrict__ out) {
    __shared__ u16 smem[32768];           // 64 KB
    u16* ldsA = smem;                     // 16 KB: x then y, swizzled A-frag order
    u16* ldsQ = smem + 8192;              // 16 KB each: [token'(128)][swz d(64)]
    u16* ldsK = smem + 16384;
    u16* ldsV = smem + 24576;
    unsigned int* ldsA32 = (unsigned int*)ldsA;

    int t = threadIdx.x;
    int lane = t & 63;
    int wid = __builtin_amdgcn_readfirstlane(t >> 6);  // 0..15
    int dq = wid & 3;                     // d-quarter
    int mh = wid >> 2;                    // token-tile pair (== p in phase 3)
    int n15 = lane & 15;
    int quad = lane >> 4;
    int b = blockIdx.x >> 9;              // 2048 blocks = 4 b x 512
    int hw0 = (blockIdx.x & 511) << 5;

    // QKV W-fragments (bf16) for this wave's d-quarter (proj frags in ph3)
    bf16x8 fq0 = load_bfrag(wq, dq*16 + n15, quad*8);
    bf16x8 fq1 = load_bfrag(wq, dq*16 + n15, 32 + quad*8);
    bf16x8 fk0 = load_bfrag(wk, dq*16 + n15, quad*8);
    bf16x8 fk1 = load_bfrag(wk, dq*16 + n15, 32 + quad*8);
    bf16x8 fv0 = load_bfrag(wv, dq*16 + n15, quad*8);
    bf16x8 fv1 = load_bfrag(wv, dq*16 + n15, 32 + quad*8);

    // stage x -> ldsA (A-frag layout, 128 tokens x 64 c, 128 B/row loads)
    {
        int rp = t >> 3, l4 = t & 7;      // rp: [p(4)][cpair(32)], l4: px/4
        int p = rp >> 5, cp = rp & 31;
        int c0 = cp*2;
        const float* r0 = x_in + (size_t)(b*256 + p*64 + c0)*HWSZ + hw0 + l4*4;
        float4 v0 = *(const float4*)r0;
        float4 v1 = *(const float4*)(r0 + HWSZ);
        int kt = c0 >> 5, qd = (c0 >> 3) & 3, j2 = (c0 & 7) >> 1;
        float a0v[4] = {v0.x, v0.y, v0.z, v0.w};
        float a1v[4] = {v1.x, v1.y, v1.z, v1.w};
        #pragma unroll
        for (int e = 0; e < 4; ++e) {
            int tau = (p << 5) + (l4 << 2) + e;
            int slot = (tau & 15) | (qd << 4);
            ldsA32[((tau >> 4)*2 + kt)*256 + sswz(slot)*4 + j2] = cvt_pk_bf16(a0v[e], a1v[e]);
        }
    }
    __syncthreads();

    // ---- phase 1: Q,K,V GEMMs (transposed: D[d][token]) ----
    int sl8 = sswz(lane)*8;
    for (int m = 0; m < 2; ++m) {
        int mt = mh*2 + m;
        bf16x8 a0 = *(const bf16x8*)(ldsA + mt*1024 + sl8);
        bf16x8 a1 = *(const bf16x8*)(ldsA + mt*1024 + 512 + sl8);
        f32x4 aq = {0.f,0.f,0.f,0.f};
        f32x4 ak = {0.f,0.f,0.f,0.f};
        f32x4 av = {0.f,0.f,0.f,0.f};
        aq = __builtin_amdgcn_mfma_f32_16x16x32_bf16(fq0, a0, aq, 0, 0, 0);
        aq = __builtin_amdgcn_mfma_f32_16x16x32_bf16(fq1, a1, aq, 0, 0, 0);
        ak = __builtin_amdgcn_mfma_f32_16x16x32_bf16(fk0, a0, ak, 0, 0, 0);
        ak = __builtin_amdgcn_mfma_f32_16x16x32_bf16(fk1, a1, ak, 0, 0, 0);
        av = __builtin_amdgcn_mfma_f32_16x16x32_bf16(fv0, a0, av, 0, 0, 0);
        av = __builtin_amdgcn_mfma_f32_16x16x32_bf16(fv1, a1, av, 0, 0, 0);
        // lane: tau = mt*16+n15 = p*32+px; d = dq*16+quad*4+r
        int tg = mt*16 + n15;
        int tok = (tg & 31)*4 + (tg >> 5);          // token' = px*4 + p
        int base = dq*4 + quad;                     // d granule (8B)
        int X = n15 & 7;                            // pair-preserving XOR swz
        int g = (base & 1) | ((((base >> 1) ^ X) & 7) << 1);
        int off = tok*64 + g*4;                     // u16 units
        uint2 pq, pk, pv;
        pq.x = cvt_pk_bf16(aq[0], aq[1]); pq.y = cvt_pk_bf16(aq[2], aq[3]);
        pk.x = cvt_pk_bf16(ak[0], ak[1]); pk.y = cvt_pk_bf16(ak[2], ak[3]);
        pv.x = cvt_pk_bf16(av[0], av[1]); pv.y = cvt_pk_bf16(av[2], av[3]);
        *(uint2*)(ldsQ + off) = pq;
        *(uint2*)(ldsK + off) = pk;
        *(uint2*)(ldsV + off) = pv;
    }
    __syncthreads();

    // ---- phase 2: attention core (thread = (pix, head, p); p = lane&3) ----
    {
        int p = t & 3;
        int hd = (t >> 2) & 7;
        int pix = t >> 5;                 // 0..31, fixed per half-wave
        int tok = pix*4 + p;
        int off = tok*64 + ((hd ^ (pix & 7)) << 3);   // 16B: d=hd*8..+7
        bf16x8 q8 = *(const bf16x8*)(ldsQ + off);
        bf16x8 k8 = *(const bf16x8*)(ldsK + off);
        bf16x8 v8 = *(const bf16x8*)(ldsV + off);
        float qv[8], kv[8];
        float sq = 0.f, sk = 0.f;
        #pragma unroll
        for (int j = 0; j < 8; ++j) {
            qv[j] = bf2f((u16)q8[j]);
            kv[j] = bf2f((u16)k8[j]);
            sq += qv[j]*qv[j];
            sk += kv[j]*kv[j];
        }
        float iq = rsqrtf(fmaxf(sq, 1e-24f));   // == 1/max(||q||,1e-12)
        float ik = rsqrtf(fmaxf(sk, 1e-24f));
        float d0 = 0.f, d1 = 0.f, d2 = 0.f, d3 = 0.f;
        #pragma unroll
        for (int j = 0; j < 8; ++j) {
            float kj = kv[j];
            d0 += qv[j]*kj;
            d1 += qv[j]*__shfl_xor(kj, 1);
            d2 += qv[j]*__shfl_xor(kj, 2);
            d3 += qv[j]*__shfl_xor(kj, 3);
        }
        float mbp = ws[OFF_MB + ((size_t)b*HWSZ + hw0 + pix)*4 + p];
        float iqrs = iq * rsc[hd];
        float s0 = d0*(iqrs*ik)                 + mbp;                  // r = p
        float s1 = d1*(iqrs*__shfl_xor(ik, 1))  + __shfl_xor(mbp, 1);   // r = p^1
        float s2 = d2*(iqrs*__shfl_xor(ik, 2))  + __shfl_xor(mbp, 2);   // r = p^2
        float s3 = d3*(iqrs*__shfl_xor(ik, 3))  + __shfl_xor(mbp, 3);   // r = p^3
        float mx = fmaxf(fmaxf(s0, s1), fmaxf(s2, s3));
        float e0 = __expf(s0-mx), e1 = __expf(s1-mx);
        float e2 = __expf(s2-mx), e3 = __expf(s3-mx);
        float inv = 1.0f / (e0+e1+e2+e3);
        float w0 = e0*inv, w1 = e1*inv, w2 = e2*inv, w3 = e3*inv;
        float y[8];
        #pragma unroll
        for (int j = 0; j < 8; ++j) {
            float vj = bf2f((u16)v8[j]);
            y[j] = w0*vj + w1*__shfl_xor(vj, 1)
                 + w2*__shfl_xor(vj, 2) + w3*__shfl_xor(vj, 3);
        }
        // y -> ldsA A-frag layout (c = hd*8+j), tau = p*32 + pix
        int tau = (p << 5) + pix;
        unsigned int pk4[4];
        pk4[0] = cvt_pk_bf16(y[0], y[1]); pk4[1] = cvt_pk_bf16(y[2], y[3]);
        pk4[2] = cvt_pk_bf16(y[4], y[5]); pk4[3] = cvt_pk_bf16(y[6], y[7]);
        int slot = (tau & 15) | ((hd & 3) << 4);
        *(uint4*)(ldsA32 + ((tau >> 4)*2 + (hd >> 2))*256 + sswz(slot)*4) = *(uint4*)pk4;
    }
    __syncthreads();

    // ---- phase 3: proj GEMM + bias, direct store from registers ----
    bf16x8 fp0 = load_bfrag(wp, dq*16 + n15, quad*8);
    bf16x8 fp1 = load_bfrag(wp, dq*16 + n15, 32 + quad*8);
    float4 b4 = *(const float4*)(bpj + dq*16 + quad*4);
    for (int m = 0; m < 2; ++m) {
        int mt = mh*2 + m;                // tau tile; p = mh, px-half = m
        bf16x8 a0 = *(const bf16x8*)(ldsA + mt*1024 + sl8);
        bf16x8 a1 = *(const bf16x8*)(ldsA + mt*1024 + 512 + sl8);
        f32x4 ao = {0.f,0.f,0.f,0.f};
        ao = __builtin_amdgcn_mfma_f32_16x16x32_bf16(fp0, a0, ao, 0, 0, 0);
        ao = __builtin_amdgcn_mfma_f32_16x16x32_bf16(fp1, a1, ao, 0, 0, 0);
        // lane: px = m*16+n15, d = dq*16+quad*4+r; wave covers both 64B halves
        int px = m*16 + n15;
        size_t obase = ((size_t)((b*4 + mh)*64 + dq*16 + quad*4))*HWSZ + hw0 + px;
        out[obase]          = ao[0] + b4.x;
        out[obase +   HWSZ] = ao[1] + b4.y;
        out[obase + 2*HWSZ] = ao[2] + b4.z;
        out[obase + 3*HWSZ] = ao[3] + b4.w;
    }
}

extern "C" void kernel_launch(void* const* d_in, const int* in_sizes, int n_in,
                              void* d_out, int out_size, void* d_ws, size_t ws_size,
                              hipStream_t stream) {
    const float* x_in  = (const float*)d_in[0];
    const float* mask  = (const float*)d_in[1];
    const float* wq    = (const float*)d_in[2];
    const float* wk    = (const float*)d_in[3];
    const float* wv    = (const float*)d_in[4];
    const float* wproj = (const float*)d_in[5];
    const float* bproj = (const float*)d_in[6];
    const float* resc  = (const float*)d_in[7];
    const float* dww   = (const float*)d_in[8];
    const float* dwb   = (const float*)d_in[9];
    const float* pww   = (const float*)d_in[10];
    float* ws = (float*)d_ws;
    float* outp = (float*)d_out;

    hipLaunchKernelGGL(mask_kernel, dim3(256), dim3(1024), 0, stream,
                       mask, dww, dwb, pww, ws);
    hipLaunchKernelGGL(attn_kernel, dim3(2048), dim3(1024), 0, stream,
                       x_in, wq, wk, wv, wproj, bproj, resc, ws, outp);
}

// Round 4
// 240.917 us; speedup vs baseline: 1.1131x; 1.0840x over previous
//
#include <hip/hip_runtime.h>
#include <hip/hip_bf16.h>

#define HSZ 128
#define WSZ 128
#define HWSZ (HSZ*WSZ)      // 16384
#define NB 4

// ws layout (float offsets)
#define OFF_MB 0            // NPIX*4 floats: mask bias per (pixel, p)

typedef unsigned short u16;
typedef __attribute__((ext_vector_type(8))) short bf16x8;
typedef __attribute__((ext_vector_type(4))) float f32x4;

__device__ __forceinline__ float bf2f(u16 u) {
    return __uint_as_float(((unsigned int)u) << 16);
}
// packed fp32x2 -> bf16x2 (v_cvt_pk_bf16_f32 on gfx950), RNE
__device__ __forceinline__ unsigned int cvt_pk_bf16(float lo, float hi) {
    __hip_bfloat162 h = __float22bfloat162_rn(make_float2(lo, hi));
    return *(unsigned int*)&h;
}
// A-frag slot swizzle: bijective on 0..63, spreads 16B slot starts over banks
__device__ __forceinline__ int sswz(int s) { return s ^ (s >> 3); }
// quad_perm DPP xor-shuffles: VALU, no LDS pipe (vs __shfl_xor -> ds_bpermute)
__device__ __forceinline__ float qp1(float x) {   // lane ^ 1: [1,0,3,2]
    return __uint_as_float(__builtin_amdgcn_mov_dpp(__float_as_uint(x), 0xB1, 0xF, 0xF, false));
}
__device__ __forceinline__ float qp2(float x) {   // lane ^ 2: [2,3,0,1]
    return __uint_as_float(__builtin_amdgcn_mov_dpp(__float_as_uint(x), 0x4E, 0xF, 0xF, false));
}
__device__ __forceinline__ float qp3(float x) {   // lane ^ 3: [3,2,1,0]
    return __uint_as_float(__builtin_amdgcn_mov_dpp(__float_as_uint(x), 0x1B, 0xF, 0xF, false));
}
// lane's W-fragment: W[drow][k0..k0+7] as bf16 (lane&15 -> row, quad -> k-group)
__device__ __forceinline__ bf16x8 load_bfrag(const float* W, int drow, int k0) {
    float4 a = *(const float4*)(W + drow*64 + k0);
    float4 b = *(const float4*)(W + drow*64 + k0 + 4);
    unsigned int u[4];
    u[0] = cvt_pk_bf16(a.x, a.y); u[1] = cvt_pk_bf16(a.z, a.w);
    u[2] = cvt_pk_bf16(b.x, b.y); u[3] = cvt_pk_bf16(b.z, b.w);
    return *(bf16x8*)u;
}

// ---------------- Kernel 1: mask branch -> mb[pix][p] ----------------------
// mb = colmean(pw_w) . gelu(dwconv3x3(mask)+dw_b)   (mean(pw_b) cancels)
__global__ __launch_bounds__(1024) void mask_kernel(const float* __restrict__ mask,
                                                    const float* __restrict__ dww,
                                                    const float* __restrict__ dwb,
                                                    const float* __restrict__ pww,
                                                    float* __restrict__ ws) {
    __shared__ float red[4][256][4];   // 16 KB
    __shared__ float cmS[64];
    int tid = threadIdx.x;
    if (tid < 64) {                    // fold colmean(pw_w) into this kernel
        float s = 0.f;
        for (int co = 0; co < 64; ++co) s += pww[co*64 + tid];
        cmS[tid] = s * (1.0f/64.0f);
    }
    __syncthreads();
    int bid = blockIdx.x;              // 256 blocks: [bp(16)][hgroup(16)]
    int bp = bid >> 4;
    int hg = bid & 15;
    int cq = tid >> 8;                 // channel quarter 0..3
    int t = tid & 255;                 // pixel slot: 8 rows x 32 colgroups
    int h = hg*8 + (t >> 5);
    int w0 = (t & 31) << 2;
    const float* mb_ = mask + (size_t)bp*64*HWSZ;
    int hm = h > 0 ? h-1 : 0;
    int hp = h < 127 ? h+1 : 127;
    float vt = h > 0 ? 1.f : 0.f;
    float vb = h < 127 ? 1.f : 0.f;
    float vl = w0 > 0 ? 1.f : 0.f;
    float vr = w0 < 124 ? 1.f : 0.f;
    int wl = w0 > 0 ? w0-1 : 0;
    int wr = w0 < 124 ? w0+4 : 127;
    float acc0=0.f, acc1=0.f, acc2=0.f, acc3=0.f;
    for (int ci = 0; ci < 16; ++ci) {
        int c = cq*16 + ci;
        const float* rc = mb_ + c*HWSZ;
        const float* r0 = rc + hm*WSZ;
        const float* r1 = rc + h*WSZ;
        const float* r2 = rc + hp*WSZ;
        float4 m0 = *(const float4*)(r0 + w0);
        float4 m1 = *(const float4*)(r1 + w0);
        float4 m2 = *(const float4*)(r2 + w0);
        float L0 = r0[wl]*vl, L1 = r1[wl]*vl, L2 = r2[wl]*vl;
        float R0 = r0[wr]*vr, R1 = r1[wr]*vr, R2 = r2[wr]*vr;
        float w00 = dww[c*9+0]*vt, w01 = dww[c*9+1]*vt, w02 = dww[c*9+2]*vt;
        float w10 = dww[c*9+3],    w11 = dww[c*9+4],    w12 = dww[c*9+5];
        float w20 = dww[c*9+6]*vb, w21 = dww[c*9+7]*vb, w22 = dww[c*9+8]*vb;
        float bb = dwb[c];
        float s0 = bb + w00*L0   + w01*m0.x + w02*m0.y
                      + w10*L1   + w11*m1.x + w12*m1.y
                      + w20*L2   + w21*m2.x + w22*m2.y;
        float s1 = bb + w00*m0.x + w01*m0.y + w02*m0.z
                      + w10*m1.x + w11*m1.y + w12*m1.z
                      + w20*m2.x + w21*m2.y + w22*m2.z;
        float s2 = bb + w00*m0.y + w01*m0.z + w02*m0.w
                      + w10*m1.y + w11*m1.z + w12*m1.w
                      + w20*m2.y + w21*m2.z + w22*m2.w;
        float s3 = bb + w00*m0.z + w01*m0.w + w02*R0
                      + w10*m1.z + w11*m1.w + w12*R1
                      + w20*m2.z + w21*m2.w + w22*R2;
        float cmc = cmS[c];
        acc0 += cmc * (0.5f*s0*(1.f + erff(s0*0.70710678118654752f)));
        acc1 += cmc * (0.5f*s1*(1.f + erff(s1*0.70710678118654752f)));
        acc2 += cmc * (0.5f*s2*(1.f + erff(s2*0.70710678118654752f)));
        acc3 += cmc * (0.5f*s3*(1.f + erff(s3*0.70710678118654752f)));
    }
    red[cq][t][0] = acc0;
    red[cq][t][1] = acc1;
    red[cq][t][2] = acc2;
    red[cq][t][3] = acc3;
    __syncthreads();
    if (tid < 256) {
        int b = bp >> 2, p = bp & 3;
        size_t base = (size_t)b*HWSZ + h*WSZ + w0;
        #pragma unroll
        for (int e = 0; e < 4; ++e) {
            float v = red[0][tid][e] + red[1][tid][e] + red[2][tid][e] + red[3][tid][e];
            ws[OFF_MB + (base+e)*4 + p] = v;
        }
    }
}

// ---------------- Kernel 2: MFMA qkv + attention + MFMA proj ---------------
// 32 px/block, 512 thr (8 waves), 48 KB LDS -> 3 blocks/CU = 24 waves/CU,
// three INDEPENDENT blocks per CU (staggered phases, unlike R3's 2 lockstep
// 16-wave blocks). V rides registers through ph1 and lands in the dead
// x-staging region; y lands in the dead Q region (2 extra cheap barriers).
// All cross-polarization exchange via DPP quad_perm (VALU), not ds_bpermute.
__global__ __launch_bounds__(512, 6) void attn_kernel(const float* __restrict__ x_in,
                                                      const float* __restrict__ wq,
                                                      const float* __restrict__ wk,
                                                      const float* __restrict__ wv,
                                                      const float* __restrict__ wp,
                                                      const float* __restrict__ bpj,
                                                      const float* __restrict__ rsc,
                                                      const float* __restrict__ ws,
                                                      float* __restrict__ out) {
    __shared__ u16 smem[24576];           // 48 KB
    u16* ldsAV = smem;                    // 16 KB: x A-frags (stage/ph1), V token' (ph2)
    u16* ldsQ  = smem + 8192;             // 16 KB: Q token' (ph2), y A-frags (ph3)
    u16* ldsK  = smem + 16384;            // 16 KB: K token'
    unsigned int* ldsAV32 = (unsigned int*)ldsAV;
    unsigned int* ldsQ32  = (unsigned int*)ldsQ;

    int t = threadIdx.x;
    int lane = t & 63;
    int wid = __builtin_amdgcn_readfirstlane(t >> 6);  // 0..7
    int dq = wid & 3;                     // d-quarter
    int half = wid >> 2;                  // token-tile half (mt 0..3 / 4..7)
    int n15 = lane & 15;
    int quad = lane >> 4;
    int b = blockIdx.x >> 9;              // 2048 blocks = 4 b x 512
    int hw0 = (blockIdx.x & 511) << 5;

    // W-fragments (bf16) for this wave's d-quarter
    bf16x8 fq0 = load_bfrag(wq, dq*16 + n15, quad*8);
    bf16x8 fq1 = load_bfrag(wq, dq*16 + n15, 32 + quad*8);
    bf16x8 fk0 = load_bfrag(wk, dq*16 + n15, quad*8);
    bf16x8 fk1 = load_bfrag(wk, dq*16 + n15, 32 + quad*8);
    bf16x8 fv0 = load_bfrag(wv, dq*16 + n15, quad*8);
    bf16x8 fv1 = load_bfrag(wv, dq*16 + n15, 32 + quad*8);
    bf16x8 fp0 = load_bfrag(wp, dq*16 + n15, quad*8);
    bf16x8 fp1 = load_bfrag(wp, dq*16 + n15, 32 + quad*8);
    float4 b4 = *(const float4*)(bpj + dq*16 + quad*4);

    // stage x -> ldsAV (A-frag layout, 128 tokens x 64 c, 128 B/row loads)
    for (int it = 0; it < 2; ++it) {
        int i = t + (it << 9);            // 0..1023: [p(4)][cpair(32)][l4(8)]
        int rp = i >> 3, l4 = i & 7;
        int p = rp >> 5, cp = rp & 31;
        int c0 = cp*2;
        const float* r0 = x_in + (size_t)(b*256 + p*64 + c0)*HWSZ + hw0 + l4*4;
        float4 v0 = *(const float4*)r0;
        float4 v1 = *(const float4*)(r0 + HWSZ);
        int kt = c0 >> 5, qd = (c0 >> 3) & 3, j2 = (c0 & 7) >> 1;
        float a0v[4] = {v0.x, v0.y, v0.z, v0.w};
        float a1v[4] = {v1.x, v1.y, v1.z, v1.w};
        #pragma unroll
        for (int e = 0; e < 4; ++e) {
            int tau = (p << 5) + (l4 << 2) + e;
            int slot = (tau & 15) | (qd << 4);
            ldsAV32[((tau >> 4)*2 + kt)*256 + sswz(slot)*4 + j2] = cvt_pk_bf16(a0v[e], a1v[e]);
        }
    }
    __syncthreads();

    // ---- phase 1: Q,K,V GEMMs (transposed: D[d][token]); V held in regs ----
    int sl8 = sswz(lane)*8;
    uint2 vreg[4];
    #pragma unroll
    for (int m = 0; m < 4; ++m) {
        int mt = half*4 + m;
        bf16x8 a0 = *(const bf16x8*)(ldsAV + mt*1024 + sl8);
        bf16x8 a1 = *(const bf16x8*)(ldsAV + mt*1024 + 512 + sl8);
        f32x4 aq = {0.f,0.f,0.f,0.f};
        f32x4 ak = {0.f,0.f,0.f,0.f};
        f32x4 av = {0.f,0.f,0.f,0.f};
        aq = __builtin_amdgcn_mfma_f32_16x16x32_bf16(fq0, a0, aq, 0, 0, 0);
        aq = __builtin_amdgcn_mfma_f32_16x16x32_bf16(fq1, a1, aq, 0, 0, 0);
        ak = __builtin_amdgcn_mfma_f32_16x16x32_bf16(fk0, a0, ak, 0, 0, 0);
        ak = __builtin_amdgcn_mfma_f32_16x16x32_bf16(fk1, a1, ak, 0, 0, 0);
        av = __builtin_amdgcn_mfma_f32_16x16x32_bf16(fv0, a0, av, 0, 0, 0);
        av = __builtin_amdgcn_mfma_f32_16x16x32_bf16(fv1, a1, av, 0, 0, 0);
        // lane: tau = mt*16+n15 = p*32+px; d = dq*16+quad*4+r
        int tg = mt*16 + n15;
        int tok = (tg & 31)*4 + (tg >> 5);          // token' = px*4 + p
        int base = dq*4 + quad;                     // d granule (8B)
        int X = n15 & 7;                            // pair-preserving XOR swz
        int g = (base & 1) | ((((base >> 1) ^ X) & 7) << 1);
        int off = tok*64 + g*4;                     // u16 units
        uint2 pq, pk;
        pq.x = cvt_pk_bf16(aq[0], aq[1]); pq.y = cvt_pk_bf16(aq[2], aq[3]);
        pk.x = cvt_pk_bf16(ak[0], ak[1]); pk.y = cvt_pk_bf16(ak[2], ak[3]);
        *(uint2*)(ldsQ + off) = pq;
        *(uint2*)(ldsK + off) = pk;
        vreg[m].x = cvt_pk_bf16(av[0], av[1]);
        vreg[m].y = cvt_pk_bf16(av[2], av[3]);
    }
    __syncthreads();                      // all A(x) reads done
    // ---- phase 1b: V regs -> ldsAV (token' layout over dead x region) ----
    #pragma unroll
    for (int m = 0; m < 4; ++m) {
        int tg = (half*4 + m)*16 + n15;
        int tok = (tg & 31)*4 + (tg >> 5);
        int base = dq*4 + quad;
        int X = n15 & 7;
        int g = (base & 1) | ((((base >> 1) ^ X) & 7) << 1);
        *(uint2*)(ldsAV + tok*64 + g*4) = vreg[m];
    }
    __syncthreads();                      // V visible

    // ---- phase 2: attention core; thread = (pix0, head, p), 2 pixels ----
    uint4 yreg[2];
    int p2 = t & 3;
    int hd = (t >> 2) & 7;
    int pix0 = t >> 5;                    // 0..15
    float rs = rsc[hd];
    #pragma unroll
    for (int u = 0; u < 2; ++u) {
        int pix = pix0 + u*16;
        int tok = pix*4 + p2;
        int off = tok*64 + ((hd ^ (pix & 7)) << 3);   // 16B: d=hd*8..+7
        bf16x8 q8 = *(const bf16x8*)(ldsQ + off);
        bf16x8 k8 = *(const bf16x8*)(ldsK + off);
        bf16x8 v8 = *(const bf16x8*)(ldsAV + off);
        float qv[8], kv[8];
        float sq = 0.f, sk = 0.f;
        #pragma unroll
        for (int j = 0; j < 8; ++j) {
            qv[j] = bf2f((u16)q8[j]);
            kv[j] = bf2f((u16)k8[j]);
            sq += qv[j]*qv[j];
            sk += kv[j]*kv[j];
        }
        float iq = rsqrtf(fmaxf(sq, 1e-24f));   // == 1/max(||q||,1e-12)
        float ik = rsqrtf(fmaxf(sk, 1e-24f));
        float d0 = 0.f, d1 = 0.f, d2 = 0.f, d3 = 0.f;
        #pragma unroll
        for (int j = 0; j < 8; ++j) {
            float kj = kv[j];
            d0 += qv[j]*kj;
            d1 += qv[j]*qp1(kj);
            d2 += qv[j]*qp2(kj);
            d3 += qv[j]*qp3(kj);
        }
        float mbp = ws[OFF_MB + ((size_t)b*HWSZ + hw0 + pix)*4 + p2];
        float iqrs = iq * rs;
        float s0 = d0*(iqrs*ik)      + mbp;       // r = p2
        float s1 = d1*(iqrs*qp1(ik)) + qp1(mbp);  // r = p2^1
        float s2 = d2*(iqrs*qp2(ik)) + qp2(mbp);  // r = p2^2
        float s3 = d3*(iqrs*qp3(ik)) + qp3(mbp);  // r = p2^3
        float mx = fmaxf(fmaxf(s0, s1), fmaxf(s2, s3));
        float e0 = __expf(s0-mx), e1 = __expf(s1-mx);
        float e2 = __expf(s2-mx), e3 = __expf(s3-mx);
        float inv = 1.0f / (e0+e1+e2+e3);
        float w0 = e0*inv, w1 = e1*inv, w2 = e2*inv, w3 = e3*inv;
        float y[8];
        #pragma unroll
        for (int j = 0; j < 8; ++j) {
            float vj = bf2f((u16)v8[j]);
            y[j] = w0*vj + w1*qp1(vj) + w2*qp2(vj) + w3*qp3(vj);
        }
        yreg[u].x = cvt_pk_bf16(y[0], y[1]);
        yreg[u].y = cvt_pk_bf16(y[2], y[3]);
        yreg[u].z = cvt_pk_bf16(y[4], y[5]);
        yreg[u].w = cvt_pk_bf16(y[6], y[7]);
    }
    __syncthreads();                      // all Q/K/V reads done
    // ---- phase 2b: y regs -> ldsQ (A-frag layout over dead Q region) ----
    #pragma unroll
    for (int u = 0; u < 2; ++u) {
        int pix = pix0 + u*16;
        int tau = (p2 << 5) + pix;        // c = hd*8+j
        int slot = (tau & 15) | ((hd & 3) << 4);
        *(uint4*)(ldsQ32 + ((tau >> 4)*2 + (hd >> 2))*256 + sswz(slot)*4) = yreg[u];
    }
    __syncthreads();                      // y visible

    // ---- phase 3: proj GEMM + bias, direct store from registers ----
    #pragma unroll
    for (int m = 0; m < 4; ++m) {
        int mt = half*4 + m;              // tau tile: p = mt>>1, px-half = mt&1
        bf16x8 a0 = *(const bf16x8*)(ldsQ + mt*1024 + sl8);
        bf16x8 a1 = *(const bf16x8*)(ldsQ + mt*1024 + 512 + sl8);
        f32x4 ao = {0.f,0.f,0.f,0.f};
        ao = __builtin_amdgcn_mfma_f32_16x16x32_bf16(fp0, a0, ao, 0, 0, 0);
        ao = __builtin_amdgcn_mfma_f32_16x16x32_bf16(fp1, a1, ao, 0, 0, 0);
        // lane: px = (mt&1)*16+n15, d = dq*16+quad*4+r
        int p = mt >> 1;
        int px = (mt & 1)*16 + n15;
        size_t obase = ((size_t)((b*4 + p)*64 + dq*16 + quad*4))*HWSZ + hw0 + px;
        out[obase]          = ao[0] + b4.x;
        out[obase +   HWSZ] = ao[1] + b4.y;
        out[obase + 2*HWSZ] = ao[2] + b4.z;
        out[obase + 3*HWSZ] = ao[3] + b4.w;
    }
}

extern "C" void kernel_launch(void* const* d_in, const int* in_sizes, int n_in,
                              void* d_out, int out_size, void* d_ws, size_t ws_size,
                              hipStream_t stream) {
    const float* x_in  = (const float*)d_in[0];
    const float* mask  = (const float*)d_in[1];
    const float* wq    = (const float*)d_in[2];
    const float* wk    = (const float*)d_in[3];
    const float* wv    = (const float*)d_in[4];
    const float* wproj = (const float*)d_in[5];
    const float* bproj = (const float*)d_in[6];
    const float* resc  = (const float*)d_in[7];
    const float* dww   = (const float*)d_in[8];
    const float* dwb   = (const float*)d_in[9];
    const float* pww   = (const float*)d_in[10];
    float* ws = (float*)d_ws;
    float* outp = (float*)d_out;

    hipLaunchKernelGGL(mask_kernel, dim3(256), dim3(1024), 0, stream,
                       mask, dww, dwb, pww, ws);
    hipLaunchKernelGGL(attn_kernel, dim3(2048), dim3(512), 0, stream,
                       x_in, wq, wk, wv, wproj, bproj, resc, ws, outp);
}